// Round 3
// baseline (212.236 us; speedup 1.0000x reference)
//
#include <hip/hip_runtime.h>

#define BB 256
#define NN 4096
#define CC 16
#define WW 10
#define LL 4087  // N - W + 1
#define EPSF 1e-5f

// global -> LDS direct copy, 16 B per lane, dest = uniform base + lane*16
#define GLOAD16(gsrc, ldst)                                                                  \
    __builtin_amdgcn_global_load_lds((const __attribute__((address_space(1))) void*)(gsrc),  \
                                     (__attribute__((address_space(3))) void*)(ldst), 16, 0, 0)

// ---------------- Kernel 0: pack + zero-pad weights into ws (512 KB) ----------------
// pk[n*16+c] = {Wr[c,n], Wi[c,n]}, zeros for n >= LL
__global__ __launch_bounds__(256) void pack_weights(const float* __restrict__ Wr,
                                                    const float* __restrict__ Wi,
                                                    float2* __restrict__ pk) {
    int tg = blockIdx.x * 256 + threadIdx.x;  // [0, 65536)
    int n = tg >> 4, c = tg & 15;
    float2 v = make_float2(0.f, 0.f);
    if (n < LL) { v.x = Wr[c * LL + n]; v.y = Wi[c * LL + n]; }
    pk[tg] = v;
}

// ---------------- Kernel 1 (R8): LDS-staged fused stage1+2+3 ----------------
// HISTORY:
//  R3: float4/lane + nontemporal loads regressed; R5: BN fusion regressed.
//  R6 FAILED: xb[16] batching under default launch_bounds -> 64-VGPR cap -> scratch
//    spill (WRITE_SIZE 319MB), 65->213us.
//  R7 NEUTRAL: (1024,4) + batched xb/wb, no spill, but fused stuck at ~65us = 3x the
//    21us x-BW floor. Direct per-lane float2 loads = 4 scattered 128B lines 8KiB apart
//    per wave instr -> DRAM row-unfriendly (fill kernel: sequential, 7 TB/s; us: ~2).
//  R8: stage x and pk tiles into LDS via global_load_lds dwordx4 (each wave instr reads
//    1KiB CONTIGUOUS; each CU streams its 512KiB x region linearly). Double-buffered
//    256-n tiles: x 32KiB + pk 34KiB (16-row halo for the w-window) per buffer = 132KiB
//    LDS. Prefetch t+1 while computing t; __syncthreads drains vmcnt per tile.
//    Per-thread: 4-n runs per tile, 13 W + 4 x LDS reads, 80 FMA. Epilogue unchanged,
//    overlaid on dead buffers.
__global__ __launch_bounds__(1024, 4) void fused_lds(const float* __restrict__ x,
                                                     const float2* __restrict__ pk,
                                                     const float* __restrict__ Wnl,
                                                     const float* __restrict__ Wor,
                                                     const float* __restrict__ Woi,
                                                     float* __restrict__ outraw) {
    // smem layout: [0,32768) xbuf0 | [32768,65536) xbuf1 | [65536,100352) pkbuf0
    //              | [100352,135168) pkbuf1 ; epilogue overlays [0,23040)
    __shared__ __align__(16) char smem[135168];

    const int b = blockIdx.x;
    const int tid = threadIdx.x;
    const int c = tid & 15;
    const int tc = tid >> 4;   // 0..63
    const int base = tc * 4;   // n-offset of this thread's run within a tile
    const int lane = tid & 63, wave = tid >> 6;
    const int l16 = lane * 16;

    const char* __restrict__ xsrc = (const char*)x + (size_t)b * (NN * CC * 8);
    const char* __restrict__ psrc = (const char*)pk;

    float fr[WW], fi[WW];
#pragma unroll
    for (int w = 0; w < WW; ++w) { fr[w] = 0.f; fi[w] = 0.f; }

    // ---- prologue: stage tile 0 (x rows [0,256), pk rows [0,272) at slot=row) ----
    {
#pragma unroll
        for (int k = 0; k < 2; ++k) {
            const int i = wave * 2 + k;
            GLOAD16(xsrc + i * 1024 + l16, smem + i * 1024);
            GLOAD16(psrc + i * 1024 + l16, smem + 65536 + i * 1024);
        }
        if (wave < 2) {
            const int i = 32 + wave;
            GLOAD16(psrc + i * 1024 + l16, smem + 65536 + i * 1024);
        }
    }
    __syncthreads();

#pragma unroll 1
    for (int t = 0; t < 16; ++t) {
        // ---- issue prefetch of tile t+1 into the other buffer ----
        if (t < 15) {
            const int t1 = t + 1, pb_ = t1 & 1;
            const char* xs = xsrc + (size_t)t1 * 32768;
            char* xd = smem + pb_ * 32768;
#pragma unroll
            for (int k = 0; k < 2; ++k) {
                const int i = wave * 2 + k;
                GLOAD16(xs + i * 1024 + l16, xd + i * 1024);
            }
            // pk rows [t1*256-16, t1*256+256): slot(m) = m - (t1*256-16)
            const char* ps = psrc + (size_t)(t1 * 256 - 16) * 128;
            char* pd = smem + 65536 + pb_ * 34816;
#pragma unroll
            for (int k = 0; k < 2; ++k) {
                const int i = wave * 2 + k;
                GLOAD16(ps + i * 1024 + l16, pd + i * 1024);
            }
            if (wave < 2) {
                const int i = 32 + wave;
                GLOAD16(ps + i * 1024 + l16, pd + i * 1024);
            }
        }

        // ---- compute tile t from buffer t&1 ----
        const float2* __restrict__ xb = (const float2*)(smem + (t & 1) * 32768);
        const float2* __restrict__ pb = (const float2*)(smem + 65536 + (t & 1) * 34816);

        // W window for this thread's 4-n run: m = t*256 + base + j - w, j=0..3, w=0..9
        // -> 13 values, k = j - w + 9
        float2 wv[13];
        if (t == 0) {  // slot(m) = m; guard m < 0 -> 0
#pragma unroll
            for (int k = 0; k < 13; ++k) {
                const int slot = base + k - 9;
                const int sc = slot < 0 ? 0 : slot;
                const float2 tmp = pb[sc * 16 + c];
                wv[k].x = (slot >= 0) ? tmp.x : 0.f;
                wv[k].y = (slot >= 0) ? tmp.y : 0.f;
            }
        } else {  // slot(m) = m - t*256 + 16 -> base + 7 + k
#pragma unroll
            for (int k = 0; k < 13; ++k) wv[k] = pb[(base + 7 + k) * 16 + c];
        }
        float2 xv[4];
#pragma unroll
        for (int j = 0; j < 4; ++j) xv[j] = xb[(base + j) * 16 + c];
#pragma unroll
        for (int j = 0; j < 4; ++j) {
#pragma unroll
            for (int w = 0; w < WW; ++w) {
                const int k = j - w + 9;  // compile-time
                fr[w] += xv[j].x * wv[k].x;
                fi[w] += xv[j].y * wv[k].y;
            }
        }
        __syncthreads();  // drains this wave's prefetch (vmcnt) + buffer handoff
    }

    // ---- reduce over tc: xor-reduce within wave, then 16 wave-partials via LDS ----
#pragma unroll
    for (int w = 0; w < WW; ++w) {
        fr[w] += __shfl_xor(fr[w], 16);
        fr[w] += __shfl_xor(fr[w], 32);
        fi[w] += __shfl_xor(fi[w], 16);
        fi[w] += __shfl_xor(fi[w], 32);
    }
    float (*red)[320] = (float (*)[320])smem;   // 20480 B, overlays dead xbuf0
    float* F2 = (float*)(smem + 20480);         // 1280 B
    float* nls = (float*)(smem + 21760);        // 1280 B
    if (lane < 16) {  // lane == c for these lanes
#pragma unroll
        for (int w = 0; w < WW; ++w) {
            red[wave][lane * 20 + w] = fr[w];
            red[wave][lane * 20 + 10 + w] = fi[w];
        }
    }
    __syncthreads();
    if (tid < 320) {
        float s = 0.f;
#pragma unroll
        for (int k = 0; k < 16; ++k) s += red[k][tid];
        F2[tid] = s;  // slot = c*20 + j*10 + w  (j=0:real, 1:imag)
    }
    __syncthreads();
    if (tid < 160) {  // amplitude scaling
        const int cc = tid / 10, w = tid % 10;
        const float a = F2[cc * 20 + w], q = F2[cc * 20 + 10 + w];
        const float amp = a * a + q * q;
        F2[cc * 20 + w] = a * amp;
        F2[cc * 20 + 10 + w] = q * amp;
    }
    __syncthreads();
    if (tid < 320) {  // nl[w,c,o] = sum_i tf[w,i] * Wnl[c,o,i]
        const int cc = tid / 20, rem = tid % 20, o = rem / 10, w = rem % 10;
        const float* __restrict__ wn = Wnl + (cc * 2 + o) * 32;
        float acc = 0.f;
#pragma unroll
        for (int i = 0; i < 16; ++i) acc += F2[i * 20 + w] * wn[i];
#pragma unroll
        for (int i = 0; i < 16; ++i) acc += F2[i * 20 + 10 + w] * wn[16 + i];
        nls[tid] = acc;  // slot = c*20 + o*10 + w
    }
    __syncthreads();
    if (tid < 32) {  // out[b,c,o] = sum_w nl[w,c,o] * Wout_o[c,w]
        const int cc = tid >> 1, o = tid & 1;
        const float* __restrict__ wo = (o == 0 ? Wor : Woi) + cc * WW;
        float acc = 0.f;
#pragma unroll
        for (int w = 0; w < WW; ++w) acc += nls[cc * 20 + o * 10 + w] * wo[w];
        outraw[b * 32 + cc * 2 + o] = acc;
    }
}

// ---------------- Fallback (no workspace): R7 register version, PK=false ----------------
__global__ __launch_bounds__(1024, 4) void fused_main_nopk(const float* __restrict__ x,
                                                           const float* __restrict__ Wr,
                                                           const float* __restrict__ Wi,
                                                           const float* __restrict__ Wnl,
                                                           const float* __restrict__ Wor,
                                                           const float* __restrict__ Woi,
                                                           float* __restrict__ outraw) {
    const int b = blockIdx.x;
    const int tid = threadIdx.x;
    const int tc = tid >> 4;
    const int c = tid & 15;
    const int n0 = tc * 64;

    const float2* __restrict__ x2 = (const float2*)x + (size_t)b * (NN * CC) + (n0 * 16 + c);

    float tr[9], ti[9];
    float fr[WW], fi[WW];
#pragma unroll
    for (int w = 0; w < WW; ++w) { fr[w] = 0.f; fi[w] = 0.f; }

#pragma unroll
    for (int j = 0; j < 9; ++j) {
        const int m = n0 - 9 + j;
        const int mc = m < 0 ? 0 : m;
        const float a = Wr[c * LL + mc], q = Wi[c * LL + mc];
        tr[j] = (m >= 0) ? a : 0.f;
        ti[j] = (m >= 0) ? q : 0.f;
    }

#pragma unroll 1
    for (int g = 0; g < 4; ++g) {
        const int nb = n0 + g * 16;
        float2 xb[16], wb[16];
#pragma unroll
        for (int p = 0; p < 16; ++p) {
            xb[p] = x2[p * 16];
            const int n = nb + p;
            const int nc2 = (n < LL) ? n : (LL - 1);
            const float a = Wr[c * LL + nc2], q = Wi[c * LL + nc2];
            wb[p].x = (n < LL) ? a : 0.f;
            wb[p].y = (n < LL) ? q : 0.f;
        }
        x2 += 256;
#pragma unroll
        for (int p = 0; p < 16; ++p) {
#pragma unroll
            for (int w = 0; w < WW; ++w) {
                const int q = p - w;
                const float wr_ = (q >= 0) ? wb[q].x : tr[q + 9];
                const float wi_ = (q >= 0) ? wb[q].y : ti[q + 9];
                fr[w] += xb[p].x * wr_;
                fi[w] += xb[p].y * wi_;
            }
        }
#pragma unroll
        for (int j = 0; j < 9; ++j) { tr[j] = wb[j + 7].x; ti[j] = wb[j + 7].y; }
    }

#pragma unroll
    for (int w = 0; w < WW; ++w) {
        fr[w] += __shfl_xor(fr[w], 16);
        fr[w] += __shfl_xor(fr[w], 32);
        fi[w] += __shfl_xor(fi[w], 16);
        fi[w] += __shfl_xor(fi[w], 32);
    }
    __shared__ float red[16][320];
    __shared__ float F2[320];
    __shared__ float nls[320];
    const int lane = tid & 63, wave = tid >> 6;
    if (lane < 16) {
#pragma unroll
        for (int w = 0; w < WW; ++w) {
            red[wave][lane * 20 + w] = fr[w];
            red[wave][lane * 20 + 10 + w] = fi[w];
        }
    }
    __syncthreads();
    if (tid < 320) {
        float s = 0.f;
#pragma unroll
        for (int k = 0; k < 16; ++k) s += red[k][tid];
        F2[tid] = s;
    }
    __syncthreads();
    if (tid < 160) {
        const int cc = tid / 10, w = tid % 10;
        const float a = F2[cc * 20 + w], q = F2[cc * 20 + 10 + w];
        const float amp = a * a + q * q;
        F2[cc * 20 + w] = a * amp;
        F2[cc * 20 + 10 + w] = q * amp;
    }
    __syncthreads();
    if (tid < 320) {
        const int cc = tid / 20, rem = tid % 20, o = rem / 10, w = rem % 10;
        const float* __restrict__ wn = Wnl + (cc * 2 + o) * 32;
        float acc = 0.f;
#pragma unroll
        for (int i = 0; i < 16; ++i) acc += F2[i * 20 + w] * wn[i];
#pragma unroll
        for (int i = 0; i < 16; ++i) acc += F2[i * 20 + 10 + w] * wn[16 + i];
        nls[tid] = acc;
    }
    __syncthreads();
    if (tid < 32) {
        const int cc = tid >> 1, o = tid & 1;
        const float* __restrict__ wo = (o == 0 ? Wor : Woi) + cc * WW;
        float acc = 0.f;
#pragma unroll
        for (int w = 0; w < WW; ++w) acc += nls[cc * 20 + o * 10 + w] * wo[w];
        outraw[b * 32 + cc * 2 + o] = acc;
    }
}

// ---------------- Kernel 2: BatchNorm in place on d_out ----------------
__global__ __launch_bounds__(256) void bnorm(float* __restrict__ out,
                                             const float* __restrict__ gamma,
                                             const float* __restrict__ beta) {
    const int c = blockIdx.x;   // [0,16)
    const int t = threadIdx.x;  // [0,256) == b
    const float v0 = out[t * 32 + c * 2 + 0];
    const float v1 = out[t * 32 + c * 2 + 1];
    float s = v0 + v1;
    float ss = v0 * v0 + v1 * v1;
#pragma unroll
    for (int off = 32; off > 0; off >>= 1) {
        s += __shfl_down(s, off, 64);
        ss += __shfl_down(ss, off, 64);
    }
    __shared__ float ls[8];
    const int wave = t >> 6, lane = t & 63;
    if (lane == 0) { ls[wave * 2] = s; ls[wave * 2 + 1] = ss; }
    __syncthreads();
    const float S = ls[0] + ls[2] + ls[4] + ls[6];
    const float SS = ls[1] + ls[3] + ls[5] + ls[7];
    const float mean = S * (1.f / 512.f);
    const float var = SS * (1.f / 512.f) - mean * mean;
    const float scale = gamma[c] * rsqrtf(var + EPSF);
    const float sh = beta[c];
    out[t * 32 + c * 2 + 0] = (v0 - mean) * scale + sh;
    out[t * 32 + c * 2 + 1] = (v1 - mean) * scale + sh;
}

extern "C" void kernel_launch(void* const* d_in, const int* in_sizes, int n_in,
                              void* d_out, int out_size, void* d_ws, size_t ws_size,
                              hipStream_t stream) {
    const float* x     = (const float*)d_in[0];
    const float* Wr    = (const float*)d_in[1];
    const float* Wi    = (const float*)d_in[2];
    const float* Wnl   = (const float*)d_in[3];
    const float* Wor   = (const float*)d_in[4];
    const float* Woi   = (const float*)d_in[5];
    const float* gamma = (const float*)d_in[6];
    const float* beta  = (const float*)d_in[7];
    float* out = (float*)d_out;

    const size_t pk_bytes = (size_t)NN * CC * sizeof(float2);  // 524288
    float2* pk = (float2*)d_ws;
    const bool use_pk = (ws_size >= pk_bytes);  // ws_size fixed -> same path every call

    if (use_pk) {
        hipLaunchKernelGGL(pack_weights, dim3(256), dim3(256), 0, stream, Wr, Wi, pk);
        hipLaunchKernelGGL(fused_lds, dim3(BB), dim3(1024), 0, stream,
                           x, pk, Wnl, Wor, Woi, out);
    } else {
        hipLaunchKernelGGL(fused_main_nopk, dim3(BB), dim3(1024), 0, stream,
                           x, Wr, Wi, Wnl, Wor, Woi, out);
    }
    hipLaunchKernelGGL(bnorm, dim3(CC), dim3(256), 0, stream, out, gamma, beta);
}